// Round 1
// baseline (521.463 us; speedup 1.0000x reference)
//
#include <hip/hip_runtime.h>
#include <hip/hip_bf16.h>

// Problem constants (fixed by setup_inputs)
#define B_   16
#define T_   2048
#define F_   64
#define A_   48
#define R_   32          // tokens per block
#define HSTR 68          // padded LDS row stride for H (floats): breaks bank conflicts

__device__ __forceinline__ float sigmoidf_(float x) {
    return 1.0f / (1.0f + __expf(-x));
}

// acc tile: rows r0,r1 x cols f0..f0+3.  pre = H @ W  (H: R_ x 64 in LDS, W: 64 x 64 in LDS)
__device__ __forceinline__ void gemm_tile(const float* __restrict__ sH,
                                          const float* __restrict__ sW,
                                          int r0, int r1, int f0,
                                          float accA[4], float accB[4])
{
    accA[0]=accA[1]=accA[2]=accA[3]=0.f;
    accB[0]=accB[1]=accB[2]=accB[3]=0.f;
#pragma unroll
    for (int kb = 0; kb < 16; ++kb) {
        float4 hA4 = *(const float4*)(sH + r0*HSTR + kb*4);
        float4 hB4 = *(const float4*)(sH + r1*HSTR + kb*4);
        float ha[4] = {hA4.x, hA4.y, hA4.z, hA4.w};
        float hb[4] = {hB4.x, hB4.y, hB4.z, hB4.w};
#pragma unroll
        for (int kk = 0; kk < 4; ++kk) {
            float4 w = *(const float4*)(sW + (kb*4+kk)*F_ + f0);
            accA[0] += ha[kk]*w.x; accA[1] += ha[kk]*w.y;
            accA[2] += ha[kk]*w.z; accA[3] += ha[kk]*w.w;
            accB[0] += hb[kk]*w.x; accB[1] += hb[kk]*w.y;
            accB[2] += hb[kk]*w.z; accB[3] += hb[kk]*w.w;
        }
    }
}

__global__ __launch_bounds__(256)
void ContextBlock_kernel(const float* __restrict__ he,
                         const float* __restrict__ W1,
                         const float* __restrict__ W2,
                         float* __restrict__ out)
{
    __shared__ float sW1[F_ * F_];        // 16 KB
    __shared__ float sW2[F_ * F_];        // 16 KB
    __shared__ float sH[R_ * HSTR];       // 8.5 KB, padded
    __shared__ float sScores[R_ * A_];    // 6 KB

    const int tid = threadIdx.x;
    const int blk = blockIdx.x;
    const int b   = blk >> 6;             // T_/R_ = 64 tiles per batch
    const int t0  = (blk & 63) * R_;

    const float* __restrict__ heB = he + (size_t)b * T_ * F_;

    // ---- stage W1, W2 into LDS (1024 float4 each)
    {
        const float4* w1v = (const float4*)W1;
        const float4* w2v = (const float4*)W2;
        float4* s1v = (float4*)sW1;
        float4* s2v = (float4*)sW2;
        for (int i = tid; i < 1024; i += 256) {
            s1v[i] = w1v[i];
            s2v[i] = w2v[i];
        }
    }
    // ---- H0 = he[t0 .. t0+31] into padded sH (32 rows x 16 float4)
    for (int i = tid; i < R_ * 16; i += 256) {
        int r  = i >> 4;
        int kv = i & 15;
        float4 v = ((const float4*)(heB + (size_t)(t0 + r) * F_))[kv];
        *((float4*)(sH + r * HSTR + kv * 4)) = v;
    }
    __syncthreads();

    // GEMM thread tile: 2 rows x 4 cols
    const int ry = tid >> 4;              // 0..15
    const int cx = tid & 15;              // 0..15
    const int r0 = ry * 2;
    const int r1 = r0 + 1;
    const int f0 = cx * 4;

    const int tg0 = t0 + r0;
    const int tg1 = t0 + r1;
    const int L0  = min(A_, (tg0 > 1 ? tg0 : 1));
    const int L1  = min(A_, (tg1 > 1 ? tg1 : 1));

    for (int a = 0; a < A_; ++a) {
        float accA[4], accB[4];

        // ---- H_new = sigmoid(H @ W1)
        gemm_tile(sH, sW1, r0, r1, f0, accA, accB);
        __syncthreads();   // all reads of old H (this GEMM + prev GEMM2) done
        {
            float4 hnA = make_float4(sigmoidf_(accA[0]), sigmoidf_(accA[1]),
                                     sigmoidf_(accA[2]), sigmoidf_(accA[3]));
            float4 hnB = make_float4(sigmoidf_(accB[0]), sigmoidf_(accB[1]),
                                     sigmoidf_(accB[2]), sigmoidf_(accB[3]));
            *(float4*)(sH + r0*HSTR + f0) = hnA;
            *(float4*)(sH + r1*HSTR + f0) = hnB;
        }
        __syncthreads();   // H_new visible

        // ---- Y = sigmoid(H_new @ W2), kept in registers
        gemm_tile(sH, sW2, r0, r1, f0, accA, accB);
        float yA0 = sigmoidf_(accA[0]), yA1 = sigmoidf_(accA[1]);
        float yA2 = sigmoidf_(accA[2]), yA3 = sigmoidf_(accA[3]);
        float yB0 = sigmoidf_(accB[0]), yB1 = sigmoidf_(accB[1]);
        float yB2 = sigmoidf_(accB[2]), yB3 = sigmoidf_(accB[3]);

        // ---- score partial: dot(Y[r], he[b, j(r,a), :]) over this thread's 4 cols
        int j0 = tg0 - L0 + a; if (j0 < 0) j0 = 0;
        int j1 = tg1 - L1 + a; if (j1 < 0) j1 = 0;
        float4 g0 = *(const float4*)(heB + (size_t)j0 * F_ + f0);
        float4 g1 = *(const float4*)(heB + (size_t)j1 * F_ + f0);
        float p0 = yA0*g0.x + yA1*g0.y + yA2*g0.z + yA3*g0.w;
        float p1 = yB0*g1.x + yB1*g1.y + yB2*g1.z + yB3*g1.w;

        // reduce across the 16 col-group lanes (xor 8,4,2,1 stays in-group)
#pragma unroll
        for (int m = 8; m >= 1; m >>= 1) {
            p0 += __shfl_xor(p0, m);
            p1 += __shfl_xor(p1, m);
        }
        if (cx == 0) {
            sScores[r0*A_ + a] = (a < L0) ? p0 : -1e9f;
            sScores[r1*A_ + a] = (a < L1) ? p1 : -1e9f;
        }
        // no barrier needed: sScores only read after final sync; sH untouched
        // until after next iteration's first barrier.
    }
    __syncthreads();       // all scores in place

    // ---- softmax over a (48) per token: 8 lanes per token, 6 scores each
    {
        const int r = tid >> 3;
        const int s = tid & 7;
        float sc[6];
#pragma unroll
        for (int i = 0; i < 6; ++i) sc[i] = sScores[r*A_ + i*8 + s];
        float m = sc[0];
#pragma unroll
        for (int i = 1; i < 6; ++i) m = fmaxf(m, sc[i]);
#pragma unroll
        for (int mm = 4; mm >= 1; mm >>= 1) m = fmaxf(m, __shfl_xor(m, mm));
        float e[6]; float sum = 0.f;
#pragma unroll
        for (int i = 0; i < 6; ++i) { e[i] = __expf(sc[i] - m); sum += e[i]; }
#pragma unroll
        for (int mm = 4; mm >= 1; mm >>= 1) sum += __shfl_xor(sum, mm);
        float inv = 1.0f / sum;
#pragma unroll
        for (int i = 0; i < 6; ++i) sScores[r*A_ + i*8 + s] = e[i] * inv;
    }
    __syncthreads();

    // ---- ctx[r, :] = sum_a w[a] * he[b, j(r,a), :]; 8 lanes x 8 floats per token
    {
        const int r  = tid >> 3;
        const int f8 = (tid & 7) * 8;
        const int tg = t0 + r;
        const int L  = min(A_, (tg > 1 ? tg : 1));
        float c[8] = {0,0,0,0,0,0,0,0};
        for (int a = 0; a < A_; ++a) {
            float w = sScores[r*A_ + a];
            int j = tg - L + a; if (j < 0) j = 0;
            const float4* gp = (const float4*)(heB + (size_t)j * F_ + f8);
            float4 gA = gp[0];
            float4 gB = gp[1];
            c[0] += w*gA.x; c[1] += w*gA.y; c[2] += w*gA.z; c[3] += w*gA.w;
            c[4] += w*gB.x; c[5] += w*gB.y; c[6] += w*gB.z; c[7] += w*gB.w;
        }
        float* op = out + ((size_t)b * T_ + tg) * F_ + f8;
        *(float4*)(op)     = make_float4(c[0], c[1], c[2], c[3]);
        *(float4*)(op + 4) = make_float4(c[4], c[5], c[6], c[7]);
    }
}

extern "C" void kernel_launch(void* const* d_in, const int* in_sizes, int n_in,
                              void* d_out, int out_size, void* d_ws, size_t ws_size,
                              hipStream_t stream) {
    const float* he = (const float*)d_in[0];
    const float* W1 = (const float*)d_in[1];
    const float* W2 = (const float*)d_in[2];
    float* out = (float*)d_out;
    // attention_len (d_in[3]) is fixed at 48; baked in as A_.
    dim3 grid(B_ * (T_ / R_));   // 1024 blocks
    dim3 block(256);
    hipLaunchKernelGGL(ContextBlock_kernel, grid, block, 0, stream, he, W1, W2, out);
}

// Round 2
// 187.864 us; speedup vs baseline: 2.7757x; 2.7757x over previous
//
#include <hip/hip_runtime.h>

// Problem constants (fixed by setup_inputs)
#define B_   16
#define T_   2048
#define F_   64
#define A_   48
#define TOK  64              // tokens per block
#define WSTR 68              // win row stride (floats): 272B, 16B-aligned, +4-bank rotate
#define HSTR 72              // H row stride (bf16):    144B, 16B-aligned, +4-bank rotate
#define SSTR 49              // score row stride (floats)
#define NWIN 111             // window rows: t0-48 .. t0+62

typedef __attribute__((ext_vector_type(8))) short short8;  // 8 bf16 = 4 VGPRs (MFMA A/B frag)
typedef __attribute__((ext_vector_type(4))) float f32x4;   // MFMA C/D frag

__device__ __forceinline__ unsigned short f2bf(float f) {
    union { float f; unsigned u; } v; v.f = f;
    unsigned r = v.u + 0x7FFFu + ((v.u >> 16) & 1u);   // round-to-nearest-even
    return (unsigned short)(r >> 16);
}
__device__ __forceinline__ float sig(float x) { return 1.0f / (1.0f + __expf(-x)); }

__global__ __launch_bounds__(256)
void ContextBlock_kernel(const float* __restrict__ he,
                         const float* __restrict__ W1,
                         const float* __restrict__ W2,
                         float* __restrict__ out)
{
    __shared__ float          sWin[NWIN * WSTR];   // 30.2 KB fp32 he window
    __shared__ unsigned short sH[TOK * HSTR];      //  9.2 KB bf16 H state, token-major
    __shared__ float          sSc[TOK * SSTR];     // 12.5 KB scores

    const int tid = threadIdx.x;
    const int b   = blockIdx.x >> 5;              // 2048/64 = 32 tiles per batch
    const int t0  = (blockIdx.x & 31) * TOK;
    const float* __restrict__ heB = he + (size_t)b * T_ * F_;

    // ---- stage he window rows (fp32). Rows with g<0 are never read.
    for (int i = tid; i < NWIN * 16; i += 256) {
        int row = i >> 4, c4 = (i & 15) * 4;
        int g = t0 - 48 + row;
        if (g >= 0) {
            float4 v = *(const float4*)(heB + (size_t)g * F_ + c4);
            *(float4*)(&sWin[row * WSTR + c4]) = v;
        }
    }
    // ---- stage H0 = he[t0..t0+63] as bf16, token-major
    for (int i = tid; i < TOK * 16; i += 256) {
        int row = i >> 4, c4 = (i & 15) * 4;
        float4 v = *(const float4*)(heB + (size_t)(t0 + row) * F_ + c4);
        unsigned p0 = (unsigned)f2bf(v.x) | ((unsigned)f2bf(v.y) << 16);
        unsigned p1 = (unsigned)f2bf(v.z) | ((unsigned)f2bf(v.w) << 16);
        *(uint2*)(&sH[row * HSTR + c4]) = make_uint2(p0, p1);
    }

    const int lane = tid & 63;
    const int wv   = tid >> 6;          // wave id: owns tokens wv*16..wv*16+15
    const int quad = lane >> 4;
    const int ml   = lane & 15;
    const int tw0  = wv * 16;

    // ---- A operand = W^T fragments, held in registers for the whole loop.
    // A[m][k] = W[k][m]; lane reads m = mt*16+ml, k = kh*32 + quad*8 + j.
    short8 aW1[4][2], aW2[4][2];
    for (int mt = 0; mt < 4; ++mt)
        for (int kh = 0; kh < 2; ++kh) {
            short8 f1, f2;
#pragma unroll
            for (int j = 0; j < 8; ++j) {
                int k = kh * 32 + quad * 8 + j;
                f1[j] = (short)f2bf(W1[k * F_ + mt * 16 + ml]);
                f2[j] = (short)f2bf(W2[k * F_ + mt * 16 + ml]);
            }
            aW1[mt][kh] = f1; aW2[mt][kh] = f2;
        }
    __syncthreads();

    const int tg = t0 + tw0 + ml;                 // this lane's token (C col)
    const int L  = min(A_, max(tg, 1));
    unsigned short* myH = &sH[(tw0 + ml) * HSTR]; // wave-private token rows

    for (int a = 0; a < A_; ++a) {
        // B-frags of current H: B[k][n], n=token=ml, k contiguous per lane
        short8 b0 = *(const short8*)(myH + quad * 8);
        short8 b1 = *(const short8*)(myH + 32 + quad * 8);

        // GEMM1: C[m][tok] = sum_k W1[k][m] H[tok][k]  ->  (H@W1)^T
        f32x4 c[4];
#pragma unroll
        for (int mt = 0; mt < 4; ++mt) {
            f32x4 z = {0.f, 0.f, 0.f, 0.f};
            z = __builtin_amdgcn_mfma_f32_16x16x32_bf16(aW1[mt][0], b0, z, 0, 0, 0);
            z = __builtin_amdgcn_mfma_f32_16x16x32_bf16(aW1[mt][1], b1, z, 0, 0, 0);
            c[mt] = z;
        }
        // sigmoid -> bf16 -> write my token's features back (4x ds_write_b64)
#pragma unroll
        for (int mt = 0; mt < 4; ++mt) {
            float s0 = sig(c[mt][0]), s1 = sig(c[mt][1]);
            float s2 = sig(c[mt][2]), s3 = sig(c[mt][3]);
            unsigned p0 = (unsigned)f2bf(s0) | ((unsigned)f2bf(s1) << 16);
            unsigned p1 = (unsigned)f2bf(s2) | ((unsigned)f2bf(s3) << 16);
            *(uint2*)(myH + mt * 16 + quad * 4) = make_uint2(p0, p1);
        }
        // GEMM2 on H_new (same-wave LDS ops are in-order: RAW safe)
        short8 d0 = *(const short8*)(myH + quad * 8);
        short8 d1 = *(const short8*)(myH + 32 + quad * 8);
        float y[4][4];
#pragma unroll
        for (int mt = 0; mt < 4; ++mt) {
            f32x4 z = {0.f, 0.f, 0.f, 0.f};
            z = __builtin_amdgcn_mfma_f32_16x16x32_bf16(aW2[mt][0], d0, z, 0, 0, 0);
            z = __builtin_amdgcn_mfma_f32_16x16x32_bf16(aW2[mt][1], d1, z, 0, 0, 0);
            y[mt][0] = sig(z[0]); y[mt][1] = sig(z[1]);
            y[mt][2] = sig(z[2]); y[mt][3] = sig(z[3]);
        }
        // score: dot(Y[tok], he[j]) — 16 features per lane, reduce across quads
        int j = tg - L + a; if (j < 0) j = 0;
        const float* wp = &sWin[(j - t0 + 48) * WSTR];
        float p = 0.f;
#pragma unroll
        for (int mt = 0; mt < 4; ++mt) {
            float4 g = *(const float4*)(wp + mt * 16 + quad * 4);
            p += y[mt][0] * g.x + y[mt][1] * g.y + y[mt][2] * g.z + y[mt][3] * g.w;
        }
        p += __shfl_xor(p, 16);
        p += __shfl_xor(p, 32);
        if (quad == 0) sSc[(tw0 + ml) * SSTR + a] = (a < L) ? p : -1e9f;
    }
    __syncthreads();

    // ---- softmax over a (48): 4 lanes per token, 12 scores each
    {
        int r = tid >> 2, s = tid & 3;
        float sc[12];
#pragma unroll
        for (int i = 0; i < 12; ++i) sc[i] = sSc[r * SSTR + i * 4 + s];
        float m = sc[0];
#pragma unroll
        for (int i = 1; i < 12; ++i) m = fmaxf(m, sc[i]);
        m = fmaxf(m, __shfl_xor(m, 1));
        m = fmaxf(m, __shfl_xor(m, 2));
        float e[12]; float sum = 0.f;
#pragma unroll
        for (int i = 0; i < 12; ++i) { e[i] = __expf(sc[i] - m); sum += e[i]; }
        sum += __shfl_xor(sum, 1);
        sum += __shfl_xor(sum, 2);
        float inv = 1.0f / sum;
#pragma unroll
        for (int i = 0; i < 12; ++i) sSc[r * SSTR + i * 4 + s] = e[i] * inv;
    }
    __syncthreads();

    // ---- ctx: 4 lanes per token, 16 features each; weights=0 where invalid
    {
        int r = tid >> 2, fc = (tid & 3) * 16;
        int tgr = t0 + r;
        int Lr = min(A_, max(tgr, 1));
        float acc[16];
#pragma unroll
        for (int q = 0; q < 16; ++q) acc[q] = 0.f;
        for (int a = 0; a < A_; ++a) {
            float wgt = sSc[r * SSTR + a];
            int j = tgr - Lr + a; if (j < 0) j = 0;
            const float* wp = &sWin[(j - t0 + 48) * WSTR + fc];
#pragma unroll
            for (int q = 0; q < 4; ++q) {
                float4 g = *(const float4*)(wp + q * 4);
                acc[q*4+0] += wgt * g.x; acc[q*4+1] += wgt * g.y;
                acc[q*4+2] += wgt * g.z; acc[q*4+3] += wgt * g.w;
            }
        }
        float* op = out + ((size_t)b * T_ + tgr) * F_ + fc;
#pragma unroll
        for (int q = 0; q < 4; ++q)
            *(float4*)(op + q * 4) = make_float4(acc[q*4], acc[q*4+1], acc[q*4+2], acc[q*4+3]);
    }
}

extern "C" void kernel_launch(void* const* d_in, const int* in_sizes, int n_in,
                              void* d_out, int out_size, void* d_ws, size_t ws_size,
                              hipStream_t stream) {
    const float* he = (const float*)d_in[0];
    const float* W1 = (const float*)d_in[1];
    const float* W2 = (const float*)d_in[2];
    float* out = (float*)d_out;
    // attention_len (d_in[3]) fixed at 48 (baked as A_)
    dim3 grid(B_ * (T_ / TOK));   // 512 blocks, 2 per CU
    dim3 block(256);
    hipLaunchKernelGGL(ContextBlock_kernel, grid, block, 0, stream, he, W1, W2, out);
}

// Round 3
// 178.382 us; speedup vs baseline: 2.9233x; 1.0532x over previous
//
#include <hip/hip_runtime.h>

// Problem constants (fixed by setup_inputs)
#define B_   16
#define T_   2048
#define F_   64
#define A_   48
#define TOK  64              // tokens per block (4 waves x 16 tokens)
#define WSTR 68              // window row stride (floats): 16B-aligned, 4-bank rotate/row
#define SSTR 49              // score row stride (floats)
#define NWIN 111             // window rows: t0-48 .. t0+62

typedef __attribute__((ext_vector_type(4))) _Float16 half4;  // MFMA 16x16x16 A/B frag
typedef __attribute__((ext_vector_type(4))) float    f32x4;  // MFMA C/D frag

__device__ __forceinline__ float sig(float x) { return 1.0f / (1.0f + __expf(-x)); }

__global__ __launch_bounds__(256)
void ContextBlock_kernel(const float* __restrict__ he,
                         const float* __restrict__ W1,
                         const float* __restrict__ W2,
                         float* __restrict__ out)
{
    __shared__ float sWin[NWIN * WSTR];   // 30.2 KB fp32 he window
    __shared__ float sSc[TOK * SSTR];     // 12.5 KB scores

    const int tid = threadIdx.x;
    const int b   = blockIdx.x >> 5;              // 32 tiles per batch
    const int t0  = (blockIdx.x & 31) * TOK;
    const float* __restrict__ heB = he + (size_t)b * T_ * F_;

    // ---- stage he window rows (fp32). Rows with g<0 are never read.
    for (int i = tid; i < NWIN * 16; i += 256) {
        int row = i >> 4, c4 = (i & 15) * 4;
        int g = t0 - 48 + row;
        if (g >= 0) {
            float4 v = *(const float4*)(heB + (size_t)g * F_ + c4);
            *(float4*)(&sWin[row * WSTR + c4]) = v;
        }
    }

    const int lane = tid & 63;
    const int wv   = tid >> 6;          // wave owns tokens wv*16 .. wv*16+15
    const int quad = lane >> 4;
    const int ml   = lane & 15;
    const int tw0  = wv * 16;
    const int tg   = t0 + tw0 + ml;     // this lane's token
    const int L    = min(A_, max(tg, 1));

    // ---- A-operand = W^T fragments (16x16x16: lane m=ml, k=kt*16+quad*4+j).
    // Held in registers for the entire 48-step loop. 64 VGPRs total.
    half4 aW1[4][4], aW2[4][4];         // [mo][kt]
    for (int mo = 0; mo < 4; ++mo)
        for (int kt = 0; kt < 4; ++kt) {
            half4 f1, f2;
#pragma unroll
            for (int j = 0; j < 4; ++j) {
                int k = kt * 16 + quad * 4 + j;
                f1[j] = (_Float16)W1[k * F_ + mo * 16 + ml];
                f2[j] = (_Float16)W2[k * F_ + mo * 16 + ml];
            }
            aW1[mo][kt] = f1; aW2[mo][kt] = f2;
        }

    // ---- H state as B-frags: hb[kt] = H[token=ml][kt*16+quad*4+j], f16.
    half4 hb[4];
#pragma unroll
    for (int kt = 0; kt < 4; ++kt) {
        float4 v = *(const float4*)(heB + (size_t)tg * F_ + kt * 16 + quad * 4);
        half4 h;
        h[0] = (_Float16)v.x; h[1] = (_Float16)v.y;
        h[2] = (_Float16)v.z; h[3] = (_Float16)v.w;
        hb[kt] = h;
    }
    __syncthreads();

    // ---- 48-step recurrence: entirely in registers.
    // Key layout identity (16x16x16): C/D reg r <-> row quad*4+r equals
    // B-frag j <-> k quad*4+j, so sigmoid(C) fragments ARE the next B-frags.
    for (int a = 0; a < A_; ++a) {
        // GEMM1: C = W1^T · H^T  (C[m][tok] per feature-tile mo)
        f32x4 c1[4];
#pragma unroll
        for (int mo = 0; mo < 4; ++mo) {
            f32x4 z = {0.f, 0.f, 0.f, 0.f};
#pragma unroll
            for (int kt = 0; kt < 4; ++kt)
                z = __builtin_amdgcn_mfma_f32_16x16x16f16(aW1[mo][kt], hb[kt], z, 0, 0, 0);
            c1[mo] = z;
        }
        // H_new = sigmoid(C) -> f16, directly in B-frag form
        half4 hbn[4];
#pragma unroll
        for (int mo = 0; mo < 4; ++mo) {
            half4 h;
            h[0] = (_Float16)sig(c1[mo][0]); h[1] = (_Float16)sig(c1[mo][1]);
            h[2] = (_Float16)sig(c1[mo][2]); h[3] = (_Float16)sig(c1[mo][3]);
            hbn[mo] = h;
        }
        // GEMM2: Y^T = W2^T · H_new^T
        f32x4 c2[4];
#pragma unroll
        for (int mo = 0; mo < 4; ++mo) {
            f32x4 z = {0.f, 0.f, 0.f, 0.f};
#pragma unroll
            for (int kt = 0; kt < 4; ++kt)
                z = __builtin_amdgcn_mfma_f32_16x16x16f16(aW2[mo][kt], hbn[kt], z, 0, 0, 0);
            c2[mo] = z;
        }
#pragma unroll
        for (int kt = 0; kt < 4; ++kt) hb[kt] = hbn[kt];

        // score: dot(sigmoid(c2) = Y[tok], he[j]) over this lane's 16 feats
        int j = tg - L + a; if (j < 0) j = 0;
        const float* wp = &sWin[(j - t0 + 48) * WSTR];
        float p = 0.f;
#pragma unroll
        for (int mo = 0; mo < 4; ++mo) {
            float4 g = *(const float4*)(wp + mo * 16 + quad * 4);
            p += sig(c2[mo][0]) * g.x + sig(c2[mo][1]) * g.y
               + sig(c2[mo][2]) * g.z + sig(c2[mo][3]) * g.w;
        }
        p += __shfl_xor(p, 16);
        p += __shfl_xor(p, 32);
        if (quad == 0) sSc[(tw0 + ml) * SSTR + a] = (a < L) ? p : -1e9f;
    }
    __syncthreads();

    // ---- softmax over a (48): 4 lanes per token, 12 scores each
    {
        int r = tid >> 2, s = tid & 3;
        float sc[12];
#pragma unroll
        for (int i = 0; i < 12; ++i) sc[i] = sSc[r * SSTR + i * 4 + s];
        float m = sc[0];
#pragma unroll
        for (int i = 1; i < 12; ++i) m = fmaxf(m, sc[i]);
        m = fmaxf(m, __shfl_xor(m, 1));
        m = fmaxf(m, __shfl_xor(m, 2));
        float e[12]; float sum = 0.f;
#pragma unroll
        for (int i = 0; i < 12; ++i) { e[i] = __expf(sc[i] - m); sum += e[i]; }
        sum += __shfl_xor(sum, 1);
        sum += __shfl_xor(sum, 2);
        float inv = 1.0f / sum;
#pragma unroll
        for (int i = 0; i < 12; ++i) sSc[r * SSTR + i * 4 + s] = e[i] * inv;
    }
    __syncthreads();

    // ---- ctx: 4 lanes per token, 16 features each
    {
        int r = tid >> 2, fc = (tid & 3) * 16;
        int tgr = t0 + r;
        int Lr = min(A_, max(tgr, 1));
        float acc[16];
#pragma unroll
        for (int q = 0; q < 16; ++q) acc[q] = 0.f;
        for (int a = 0; a < A_; ++a) {
            float wgt = sSc[r * SSTR + a];
            int j = tgr - Lr + a; if (j < 0) j = 0;
            const float* wp = &sWin[(j - t0 + 48) * WSTR + fc];
#pragma unroll
            for (int q = 0; q < 4; ++q) {
                float4 g = *(const float4*)(wp + q * 4);
                acc[q*4+0] += wgt * g.x; acc[q*4+1] += wgt * g.y;
                acc[q*4+2] += wgt * g.z; acc[q*4+3] += wgt * g.w;
            }
        }
        float* op = out + ((size_t)b * T_ + tgr) * F_ + fc;
#pragma unroll
        for (int q = 0; q < 4; ++q)
            *(float4*)(op + q * 4) = make_float4(acc[q*4], acc[q*4+1], acc[q*4+2], acc[q*4+3]);
    }
}

extern "C" void kernel_launch(void* const* d_in, const int* in_sizes, int n_in,
                              void* d_out, int out_size, void* d_ws, size_t ws_size,
                              hipStream_t stream) {
    const float* he = (const float*)d_in[0];
    const float* W1 = (const float*)d_in[1];
    const float* W2 = (const float*)d_in[2];
    float* out = (float*)d_out;
    // attention_len (d_in[3]) fixed at 48 (baked as A_)
    dim3 grid(B_ * (T_ / TOK));   // 512 blocks, 2 per CU
    dim3 block(256);
    hipLaunchKernelGGL(ContextBlock_kernel, grid, block, 0, stream, he, W1, W2, out);
}

// Round 4
// 131.167 us; speedup vs baseline: 3.9756x; 1.3600x over previous
//
#include <hip/hip_runtime.h>

// Problem constants (fixed by setup_inputs)
#define B_   16
#define T_   2048
#define F_   64
#define A_   48
#define TOK  64              // tokens per block (4 waves x 16 tokens)
#define WSTR 68              // window row stride (floats): 16B-aligned, 4-bank rotate/row
#define SSTR 49              // score row stride (floats)
#define NWIN 111             // window rows: t0-48 .. t0+62

typedef __attribute__((ext_vector_type(4))) _Float16 half4;  // MFMA 16x16x16 A/B frag
typedef __attribute__((ext_vector_type(4))) float    f32x4;  // MFMA C/D frag

// sigmoid with HW fast rcp (v_rcp_f32, ~1 ulp) instead of precise IEEE divide.
// Precise divide is ~11 insts incl. 2 div-helpers — it was the round-3 VALU hog.
__device__ __forceinline__ float sig(float x) {
    return __builtin_amdgcn_rcpf(1.0f + __expf(-x));
}

__global__ __launch_bounds__(256)
void ContextBlock_kernel(const float* __restrict__ he,
                         const float* __restrict__ W1,
                         const float* __restrict__ W2,
                         float* __restrict__ out)
{
    __shared__ float sWin[NWIN * WSTR];   // 30.2 KB fp32 he window
    __shared__ float sSc[TOK * SSTR];     // 12.5 KB scores

    const int tid = threadIdx.x;
    const int b   = blockIdx.x >> 5;              // 32 tiles per batch
    const int t0  = (blockIdx.x & 31) * TOK;
    const float* __restrict__ heB = he + (size_t)b * T_ * F_;

    // ---- stage he window rows (fp32). Rows with g<0 are never read.
    for (int i = tid; i < NWIN * 16; i += 256) {
        int row = i >> 4, c4 = (i & 15) * 4;
        int g = t0 - 48 + row;
        if (g >= 0) {
            float4 v = *(const float4*)(heB + (size_t)g * F_ + c4);
            *(float4*)(&sWin[row * WSTR + c4]) = v;
        }
    }

    const int lane = tid & 63;
    const int wv   = tid >> 6;          // wave owns tokens wv*16 .. wv*16+15
    const int quad = lane >> 4;
    const int ml   = lane & 15;
    const int tw0  = wv * 16;
    const int tg   = t0 + tw0 + ml;     // this lane's token
    const int L    = min(A_, max(tg, 1));

    // ---- A-operand = W^T fragments (16x16x16: lane m=ml, k=kt*16+quad*4+j).
    // Held in registers for the entire 48-step loop. 64 VGPRs total.
    half4 aW1[4][4], aW2[4][4];         // [mo][kt]
    for (int mo = 0; mo < 4; ++mo)
        for (int kt = 0; kt < 4; ++kt) {
            half4 f1, f2;
#pragma unroll
            for (int j = 0; j < 4; ++j) {
                int k = kt * 16 + quad * 4 + j;
                f1[j] = (_Float16)W1[k * F_ + mo * 16 + ml];
                f2[j] = (_Float16)W2[k * F_ + mo * 16 + ml];
            }
            aW1[mo][kt] = f1; aW2[mo][kt] = f2;
        }

    // ---- H state as B-frags: hb[kt] = H[token=ml][kt*16+quad*4+j], f16.
    half4 hb[4];
#pragma unroll
    for (int kt = 0; kt < 4; ++kt) {
        float4 v = *(const float4*)(heB + (size_t)tg * F_ + kt * 16 + quad * 4);
        half4 h;
        h[0] = (_Float16)v.x; h[1] = (_Float16)v.y;
        h[2] = (_Float16)v.z; h[3] = (_Float16)v.w;
        hb[kt] = h;
    }
    __syncthreads();

    // ---- 48-step recurrence: entirely in registers.
    // Layout identity (16x16x16): C/D reg r <-> row quad*4+r equals B-frag
    // j <-> k quad*4+j, so sigmoid(C) fragments ARE the next B-frags.
    for (int a = 0; a < A_; ++a) {
        // GEMM1: C = W1^T · H^T
        f32x4 c1[4];
#pragma unroll
        for (int mo = 0; mo < 4; ++mo) {
            f32x4 z = {0.f, 0.f, 0.f, 0.f};
#pragma unroll
            for (int kt = 0; kt < 4; ++kt)
                z = __builtin_amdgcn_mfma_f32_16x16x16f16(aW1[mo][kt], hb[kt], z, 0, 0, 0);
            c1[mo] = z;
        }
        // H_new = sigmoid(C) -> f16, directly in B-frag form
        half4 hbn[4];
#pragma unroll
        for (int mo = 0; mo < 4; ++mo) {
            half4 h;
            h[0] = (_Float16)sig(c1[mo][0]); h[1] = (_Float16)sig(c1[mo][1]);
            h[2] = (_Float16)sig(c1[mo][2]); h[3] = (_Float16)sig(c1[mo][3]);
            hbn[mo] = h;
        }
        // GEMM2: Y^T = W2^T · H_new^T
        f32x4 c2[4];
#pragma unroll
        for (int mo = 0; mo < 4; ++mo) {
            f32x4 z = {0.f, 0.f, 0.f, 0.f};
#pragma unroll
            for (int kt = 0; kt < 4; ++kt)
                z = __builtin_amdgcn_mfma_f32_16x16x16f16(aW2[mo][kt], hbn[kt], z, 0, 0, 0);
            c2[mo] = z;
        }
#pragma unroll
        for (int kt = 0; kt < 4; ++kt) hb[kt] = hbn[kt];

        // score: dot(sigmoid(c2) = Y[tok], he[j]) over this lane's 16 feats
        int j = tg - L + a; if (j < 0) j = 0;
        const float* wp = &sWin[(j - t0 + 48) * WSTR];
        float p = 0.f;
#pragma unroll
        for (int mo = 0; mo < 4; ++mo) {
            float4 g = *(const float4*)(wp + mo * 16 + quad * 4);
            p += sig(c2[mo][0]) * g.x + sig(c2[mo][1]) * g.y
               + sig(c2[mo][2]) * g.z + sig(c2[mo][3]) * g.w;
        }
        p += __shfl_xor(p, 16);
        p += __shfl_xor(p, 32);
        if (quad == 0) sSc[(tw0 + ml) * SSTR + a] = (a < L) ? p : -1e9f;
    }
    __syncthreads();

    // ---- softmax over a (48): 4 lanes per token, 12 scores each
    {
        int r = tid >> 2, s = tid & 3;
        float sc[12];
#pragma unroll
        for (int i = 0; i < 12; ++i) sc[i] = sSc[r * SSTR + i * 4 + s];
        float m = sc[0];
#pragma unroll
        for (int i = 1; i < 12; ++i) m = fmaxf(m, sc[i]);
        m = fmaxf(m, __shfl_xor(m, 1));
        m = fmaxf(m, __shfl_xor(m, 2));
        float e[12]; float sum = 0.f;
#pragma unroll
        for (int i = 0; i < 12; ++i) { e[i] = __expf(sc[i] - m); sum += e[i]; }
        sum += __shfl_xor(sum, 1);
        sum += __shfl_xor(sum, 2);
        float inv = __builtin_amdgcn_rcpf(sum);
#pragma unroll
        for (int i = 0; i < 12; ++i) sSc[r * SSTR + i * 4 + s] = e[i] * inv;
    }
    __syncthreads();

    // ---- ctx: 4 lanes per token, 16 features each
    {
        int r = tid >> 2, fc = (tid & 3) * 16;
        int tgr = t0 + r;
        int Lr = min(A_, max(tgr, 1));
        float acc[16];
#pragma unroll
        for (int q = 0; q < 16; ++q) acc[q] = 0.f;
        for (int a = 0; a < A_; ++a) {
            float wgt = sSc[r * SSTR + a];
            int j = tgr - Lr + a; if (j < 0) j = 0;
            const float* wp = &sWin[(j - t0 + 48) * WSTR + fc];
#pragma unroll
            for (int q = 0; q < 4; ++q) {
                float4 g = *(const float4*)(wp + q * 4);
                acc[q*4+0] += wgt * g.x; acc[q*4+1] += wgt * g.y;
                acc[q*4+2] += wgt * g.z; acc[q*4+3] += wgt * g.w;
            }
        }
        float* op = out + ((size_t)b * T_ + tgr) * F_ + fc;
#pragma unroll
        for (int q = 0; q < 4; ++q)
            *(float4*)(op + q * 4) = make_float4(acc[q*4], acc[q*4+1], acc[q*4+2], acc[q*4+3]);
    }
}

extern "C" void kernel_launch(void* const* d_in, const int* in_sizes, int n_in,
                              void* d_out, int out_size, void* d_ws, size_t ws_size,
                              hipStream_t stream) {
    const float* he = (const float*)d_in[0];
    const float* W1 = (const float*)d_in[1];
    const float* W2 = (const float*)d_in[2];
    float* out = (float*)d_out;
    // attention_len (d_in[3]) fixed at 48 (baked as A_)
    dim3 grid(B_ * (T_ / TOK));   // 512 blocks, 2 per CU
    dim3 block(256);
    hipLaunchKernelGGL(ContextBlock_kernel, grid, block, 0, stream, he, W1, W2, out);
}

// Round 6
// 126.371 us; speedup vs baseline: 4.1264x; 1.0380x over previous
//
#include <hip/hip_runtime.h>

// Problem constants (fixed by setup_inputs)
#define B_   16
#define T_   2048
#define F_   64
#define A_   48
#define TOK  64              // tokens per block (4 waves x 16 tokens)
#define WSTR 68              // window row stride (floats): 16B-aligned, 4-bank rotate/row
#define SSTR 49              // score row stride (floats)
#define NWIN 111             // window rows: t0-48 .. t0+62

typedef __attribute__((ext_vector_type(4))) _Float16 half4;  // MFMA 16x16x16 A/B frag
typedef __attribute__((ext_vector_type(2))) _Float16 half2;
typedef __attribute__((ext_vector_type(4))) float    f32x4;  // MFMA C/D frag

#define LOG2E 1.4426950408889634f

// W fragments are pre-scaled by -log2e, so MFMA output c = -log2e * (h@W).
// sigmoid(x) = 1/(1+e^{-x}) = rcp(1 + 2^c): v_exp + v_add + v_rcp, no mul.
__device__ __forceinline__ float sigp(float c) {
    return __builtin_amdgcn_rcpf(1.0f + __builtin_amdgcn_exp2f(c));
}

// pack two f32 -> two f16 (v_cvt_pkrtz_f16_f32); builtin returns __fp16x2,
// bit-cast to our _Float16x2.
__device__ __forceinline__ half2 pk2(float a, float b) {
    return __builtin_bit_cast(half2, __builtin_amdgcn_cvt_pkrtz(a, b));
}

__global__ __launch_bounds__(256)
void ContextBlock_kernel(const float* __restrict__ he,
                         const float* __restrict__ W1,
                         const float* __restrict__ W2,
                         float* __restrict__ out)
{
    __shared__ float sWin[NWIN * WSTR];   // 30.2 KB fp32 he window
    __shared__ float sSc[TOK * SSTR];     // 12.5 KB scores

    const int tid = threadIdx.x;
    const int b   = blockIdx.x >> 5;              // 32 tiles per batch
    const int t0  = (blockIdx.x & 31) * TOK;
    const float* __restrict__ heB = he + (size_t)b * T_ * F_;

    // ---- stage he window rows (fp32). Rows with g<0 are never read validly.
    for (int i = tid; i < NWIN * 16; i += 256) {
        int row = i >> 4, c4 = (i & 15) * 4;
        int g = t0 - 48 + row;
        if (g >= 0) {
            float4 v = *(const float4*)(heB + (size_t)g * F_ + c4);
            *(float4*)(&sWin[row * WSTR + c4]) = v;
        }
    }

    const int lane = tid & 63;
    const int wv   = tid >> 6;          // wave owns tokens wv*16 .. wv*16+15
    const int quad = lane >> 4;
    const int ml   = lane & 15;
    const int tw0  = wv * 16;
    const int tg   = t0 + tw0 + ml;     // this lane's token
    const int L    = min(A_, max(tg, 1));

    // ---- A-operand = (-log2e * W^T) fragments, registers for the whole loop.
    // 16x16x16 layout: lane m=ml, k=kt*16+quad*4+j.
    half4 aW1[4][4], aW2[4][4];         // [mo][kt]
    for (int mo = 0; mo < 4; ++mo)
        for (int kt = 0; kt < 4; ++kt) {
            half4 f1, f2;
#pragma unroll
            for (int j = 0; j < 4; ++j) {
                int k = kt * 16 + quad * 4 + j;
                f1[j] = (_Float16)(-LOG2E * W1[k * F_ + mo * 16 + ml]);
                f2[j] = (_Float16)(-LOG2E * W2[k * F_ + mo * 16 + ml]);
            }
            aW1[mo][kt] = f1; aW2[mo][kt] = f2;
        }

    // ---- H state as B-frags: hb[kt] = H[token=ml][kt*16+quad*4+j], f16.
    half4 hb[4];
#pragma unroll
    for (int kt = 0; kt < 4; ++kt) {
        float4 v = *(const float4*)(heB + (size_t)tg * F_ + kt * 16 + quad * 4);
        half4 h;
        h[0] = (_Float16)v.x; h[1] = (_Float16)v.y;
        h[2] = (_Float16)v.z; h[3] = (_Float16)v.w;
        hb[kt] = h;
    }
    __syncthreads();

    // ---- 48-step recurrence, fully in registers.
    // Critical path is only GEMM1 -> H-sigmoid -> GEMM1(next): GEMM2, Y-sigmoid
    // and the score hang off it. unroll 4 lets the scheduler overlap them
    // across iterations (VGPRs are free: occupancy is grid-capped at 2 w/SIMD).
#pragma unroll 4
    for (int a = 0; a < A_; ++a) {
        // GEMM1: C = (-log2e W1^T) · H^T
        f32x4 c1[4];
#pragma unroll
        for (int mo = 0; mo < 4; ++mo) {
            f32x4 z = {0.f, 0.f, 0.f, 0.f};
#pragma unroll
            for (int kt = 0; kt < 4; ++kt)
                z = __builtin_amdgcn_mfma_f32_16x16x16f16(aW1[mo][kt], hb[kt], z, 0, 0, 0);
            c1[mo] = z;
        }
        // H_new = sigmoid -> f16 B-frags (pkrtz packs 2 f32->2 f16 per inst)
#pragma unroll
        for (int mo = 0; mo < 4; ++mo) {
            half2 lo = pk2(sigp(c1[mo][0]), sigp(c1[mo][1]));
            half2 hi = pk2(sigp(c1[mo][2]), sigp(c1[mo][3]));
            half4 h; h[0] = lo[0]; h[1] = lo[1]; h[2] = hi[0]; h[3] = hi[1];
            hb[mo] = h;
        }
        // GEMM2: C2 = (-log2e W2^T) · H_new^T   (off the recurrence path)
        f32x4 c2[4];
#pragma unroll
        for (int mo = 0; mo < 4; ++mo) {
            f32x4 z = {0.f, 0.f, 0.f, 0.f};
#pragma unroll
            for (int kt = 0; kt < 4; ++kt)
                z = __builtin_amdgcn_mfma_f32_16x16x16f16(aW2[mo][kt], hb[kt], z, 0, 0, 0);
            c2[mo] = z;
        }
        // score: dot(Y[tok], he[j]) over this lane's 16 feats
        int j = tg - L + a; if (j < 0) j = 0;
        const float* wp = &sWin[(j - t0 + 48) * WSTR];
        float p = 0.f;
#pragma unroll
        for (int mo = 0; mo < 4; ++mo) {
            float4 g = *(const float4*)(wp + mo * 16 + quad * 4);
            p += sigp(c2[mo][0]) * g.x + sigp(c2[mo][1]) * g.y
               + sigp(c2[mo][2]) * g.z + sigp(c2[mo][3]) * g.w;
        }
        p += __shfl_xor(p, 16);
        p += __shfl_xor(p, 32);
        if (quad == 0) sSc[(tw0 + ml) * SSTR + a] = (a < L) ? p : -1e9f;
    }
    __syncthreads();

    // ---- softmax over a (48): 4 lanes per token, 12 scores each
    {
        int r = tid >> 2, s = tid & 3;
        float sc[12];
#pragma unroll
        for (int i = 0; i < 12; ++i) sc[i] = sSc[r * SSTR + i * 4 + s];
        float m = sc[0];
#pragma unroll
        for (int i = 1; i < 12; ++i) m = fmaxf(m, sc[i]);
        m = fmaxf(m, __shfl_xor(m, 1));
        m = fmaxf(m, __shfl_xor(m, 2));
        float e[12]; float sum = 0.f;
#pragma unroll
        for (int i = 0; i < 12; ++i) { e[i] = __expf(sc[i] - m); sum += e[i]; }
        sum += __shfl_xor(sum, 1);
        sum += __shfl_xor(sum, 2);
        float inv = __builtin_amdgcn_rcpf(sum);
#pragma unroll
        for (int i = 0; i < 12; ++i) sSc[r * SSTR + i * 4 + s] = e[i] * inv;
    }
    __syncthreads();

    // ---- ctx: 4 lanes per token, 16 features each
    {
        int r = tid >> 2, fc = (tid & 3) * 16;
        int tgr = t0 + r;
        int Lr = min(A_, max(tgr, 1));
        float acc[16];
#pragma unroll
        for (int q = 0; q < 16; ++q) acc[q] = 0.f;
        for (int a = 0; a < A_; ++a) {
            float wgt = sSc[r * SSTR + a];
            int j = tgr - Lr + a; if (j < 0) j = 0;
            const float* wp = &sWin[(j - t0 + 48) * WSTR + fc];
#pragma unroll
            for (int q = 0; q < 4; ++q) {
                float4 g = *(const float4*)(wp + q * 4);
                acc[q*4+0] += wgt * g.x; acc[q*4+1] += wgt * g.y;
                acc[q*4+2] += wgt * g.z; acc[q*4+3] += wgt * g.w;
            }
        }
        float* op = out + ((size_t)b * T_ + tgr) * F_ + fc;
#pragma unroll
        for (int q = 0; q < 4; ++q)
            *(float4*)(op + q * 4) = make_float4(acc[q*4], acc[q*4+1], acc[q*4+2], acc[q*4+3]);
    }
}

extern "C" void kernel_launch(void* const* d_in, const int* in_sizes, int n_in,
                              void* d_out, int out_size, void* d_ws, size_t ws_size,
                              hipStream_t stream) {
    const float* he = (const float*)d_in[0];
    const float* W1 = (const float*)d_in[1];
    const float* W2 = (const float*)d_in[2];
    float* out = (float*)d_out;
    // attention_len (d_in[3]) fixed at 48 (baked as A_)
    dim3 grid(B_ * (T_ / TOK));   // 512 blocks, 2 per CU
    dim3 block(256);
    hipLaunchKernelGGL(ContextBlock_kernel, grid, block, 0, stream, he, W1, W2, out);
}